// Round 4
// baseline (473.492 us; speedup 1.0000x reference)
//
#include <hip/hip_runtime.h>

#define LL 256   // sequence length
#define EE 64    // embed dim
#define HH 64    // hidden dim
#define GG 256   // 4*H gates
#define VV 6000  // vocab
#define NSEQ 16  // sequences per block (full MFMA tile, no waste)
#define ROWP 72  // padded LDS row stride in bf16 elems (144 B, 16B-aligned)
#define VBLK 375 // phase-1 blocks per direction (6000/16)

typedef __bf16 bf16_t;
typedef bf16_t bf16x8 __attribute__((ext_vector_type(8)));
typedef float  f32x4  __attribute__((ext_vector_type(4)));

union BfPack {
    unsigned short u[8];
    bf16x8 v;
};

__device__ __forceinline__ unsigned short f2bf(float f) {
    return __builtin_bit_cast(unsigned short, (__bf16)f);
}

#define LOG2E 1.44269504088896340736f

// exp2+rcp activations (R1: removed IEEE div sequences). Inf-safe both ends.
__device__ __forceinline__ float sigm(float x) {
    float e = __builtin_amdgcn_exp2f(-LOG2E * x);          // e^{-x}
    return __builtin_amdgcn_rcpf(1.0f + e);
}
__device__ __forceinline__ float tanh_fast(float x) {
    float e = __builtin_amdgcn_exp2f((2.0f * LOG2E) * x);  // e^{2x}
    return 1.0f - 2.0f * __builtin_amdgcn_rcpf(e + 1.0f);
}

// lgkm-only barrier (R0->R1: 567->415 us): cross-wave deps are LDS-only;
// out-stores and pre-gathers stay in flight across it (vmcnt untouched).
#define LGKM_BARRIER() asm volatile("s_waitcnt lgkmcnt(0)\n\ts_barrier" ::: "memory")

// ---------------- phase 1: embedPre[dir][v][swz(g)] = embed@Wk + b ----------
// x_t @ Wk == (embed @ Wk)[id] : the whole input projection is a table.
// Swizzled layout: pos = ((g>>4)&3)*64 + (g&15)*4 + (g>>6), so that phase-2
// lane (w,quad,l15) reads its 4 gate values for one seq-row as ONE dwordx4 at
// [id*256 + w*64 + l15*4], 16 lanes = 256 B contiguous per quad-group.
__global__ __launch_bounds__(256)
void embed_pre_kernel(const float* __restrict__ embed,
                      const float* __restrict__ Wk_f, const float* __restrict__ b_f,
                      const float* __restrict__ Wk_b, const float* __restrict__ b_b,
                      float* __restrict__ pre)
{
    const int bid = blockIdx.x;
    const int dir = bid / VBLK;
    const int v0  = (bid % VBLK) * 16;
    const float* Wk = dir ? Wk_b : Wk_f;
    const float* bv = dir ? b_b  : b_f;
    float* dst = pre + (size_t)dir * VV * GG;

    const int tid = threadIdx.x;
    const int r   = tid >> 4;    // v-row 0..15
    const int cg  = tid & 15;    // col residue; thread owns g = k*16+cg

    __shared__ float sW[16][GG];   // 16 KB per E-chunk
    __shared__ float sE[16][17];   // 16 rows x 16 e, padded

    float acc[16];
    #pragma unroll
    for (int k = 0; k < 16; ++k) acc[k] = 0.f;

    for (int ec = 0; ec < 4; ++ec) {
        {   // stage Wk rows ec*16..+15 (coalesced float4) + embed chunk
            int er = tid >> 4;
            int c0 = (tid & 15) * 16;
            const float* src = &Wk[(size_t)(ec * 16 + er) * GG + c0];
            *(float4*)&sW[er][c0 + 0]  = *(const float4*)(src + 0);
            *(float4*)&sW[er][c0 + 4]  = *(const float4*)(src + 4);
            *(float4*)&sW[er][c0 + 8]  = *(const float4*)(src + 8);
            *(float4*)&sW[er][c0 + 12] = *(const float4*)(src + 12);
            sE[er][tid & 15] = embed[(size_t)(v0 + er) * EE + ec * 16 + (tid & 15)];
        }
        __syncthreads();
        #pragma unroll
        for (int e = 0; e < 16; ++e) {
            float xe = sE[r][e];
            #pragma unroll
            for (int k = 0; k < 16; ++k)
                acc[k] += xe * sW[e][k * 16 + cg];   // 16 consecutive banks, CF
        }
        __syncthreads();
    }
    #pragma unroll
    for (int k = 0; k < 16; ++k) {
        int g = k * 16 + cg;
        int pos = ((g >> 4) & 3) * 64 + (g & 15) * 4 + (g >> 6);
        dst[(size_t)(v0 + r) * GG + pos] = acc[k] + bv[g];
    }
}

// ---------------- phase 2: recurrence only (h@Wr per step) ------------------
// One block = 16 seqs, one direction, 4 waves. Depth-2 ping-pong register
// prefetch of the pre-gathers (load->use distance = 2 steps ~ 3500 cyc >>
// worst-case HBM-miss ~900 cyc): R3 counters showed FETCH_SIZE 375 MB -- the
// random 16 B/lane gathers from the 12.3 MB table miss the 4 MB per-XCD L2,
// and at depth-1 that latency leaked into the step. out-stores are
// nontemporal: 262 MB of streamed writes must not evict the pre table from L2.
__global__ __launch_bounds__(256, 1)
void bilstm_mfma(const int* __restrict__ ids,
                 const float* __restrict__ Wr_f, const float* __restrict__ Wr_b,
                 const float* __restrict__ pre,
                 float* __restrict__ out)
{
    const int dir = blockIdx.x >> 7;    // 0 fwd, 1 bwd
    const int grp = blockIdx.x & 127;
    const int n0  = grp * NSEQ;
    const int tid  = threadIdx.x;
    const int w    = tid >> 6;
    const int lane = tid & 63;
    const int l15  = lane & 15;
    const int quad = lane >> 4;
    const int j    = w * 16 + l15;      // gate sub-index in [0,64)

    const float* Wr = dir ? Wr_b : Wr_f;
    const float* preT = pre + (size_t)dir * VV * GG;
    const int coff = w * 64 + l15 * 4;  // lane's fixed swizzled col offset

    __shared__ __align__(16) short s_h[2][NSEQ][ROWP];  // 4.5 KB
    __shared__ int s_ids[NSEQ][LL + 1];                 // padded: row stride 257

    // stage ids (coalesced)
    for (int p = tid; p < NSEQ * LL; p += 256) {
        int m = p >> 8, t = p & 255;
        s_ids[m][t] = ids[(size_t)(n0 + m) * LL + t];
    }
    // zero both h buffers (h0 = 0)
    for (int p = tid; p < 2 * NSEQ * ROWP; p += 256)
        (&s_h[0][0][0])[p] = 0;

    __syncthreads();

    // Wr B-fragments only (K=64): lane holds B[k = kc*32 + quad*8 + e][l15]
    bf16x8 bfrag[4][2];
    #pragma unroll
    for (int tt = 0; tt < 4; ++tt) {
        int g = tt * 64 + j;
        #pragma unroll
        for (int kc = 0; kc < 2; ++kc) {
            BfPack pk;
            #pragma unroll
            for (int e = 0; e < 8; ++e) {
                int kg = kc * 32 + quad * 8 + e;
                pk.u[e] = f2bf(Wr[(size_t)kg * GG + g]);
            }
            bfrag[tt][kc] = pk.v;
        }
    }

    // ping-pong prefetch buffers: PA serves even ts, PB odd ts
    f32x4 PA[4], PB[4];
    {
        int t0 = dir ? (LL - 1) : 0;
        int t1 = dir ? (LL - 2) : 1;
        #pragma unroll
        for (int r = 0; r < 4; ++r) {
            PA[r] = *(const f32x4*)&preT[(size_t)s_ids[quad * 4 + r][t0] * GG + coff];
            PB[r] = *(const f32x4*)&preT[(size_t)s_ids[quad * 4 + r][t1] * GG + coff];
        }
    }

    float c[4] = {0.f, 0.f, 0.f, 0.f};

    // strength-reduced out pointers: advance +-256 floats per timestep
    const int tstep = dir ? -(2 * HH) : (2 * HH);
    float* optr[4];
    {
        const int t0 = dir ? (LL - 1) : 0;
        #pragma unroll
        for (int r = 0; r < 4; ++r)
            optr[r] = out + ((size_t)(n0 + quad * 4 + r) * LL + t0) * (2 * HH) + dir * HH + j;
    }

    // one sub-step; P is the ping-pong buffer owning this parity
    auto do_step = [&](int ts, f32x4 (&P)[4]) {
        const int rb = ts & 1, wb = (ts + 1) & 1;

        // consume P into MFMA C-seeds (reads complete before the refill below
        // rewrites the same registers -- program order handles the WAR)
        f32x4 cIn[4];
        #pragma unroll
        for (int tt = 0; tt < 4; ++tt)
            cIn[tt] = (f32x4){P[0][tt], P[1][tt], P[2][tt], P[3][tt]};

        // refill P for ts+2: issued here, consumed 2 barriers later
        if (ts + 2 < LL) {
            int tn = dir ? (LL - 3 - ts) : (ts + 2);
            #pragma unroll
            for (int r = 0; r < 4; ++r)
                P[r] = *(const f32x4*)&preT[(size_t)s_ids[quad * 4 + r][tn] * GG + coff];
        }

        // h A-fragments: lane reads A[m=l15][k=quad*8..+7] (ds_read_b128)
        bf16x8 ah0 = *(const bf16x8*)&s_h[rb][l15][quad * 8];
        bf16x8 ah1 = *(const bf16x8*)&s_h[rb][l15][32 + quad * 8];

        // z = pre (C-seed: bias + x@Wk folded) + h@Wr, 4 independent chains
        f32x4 acc[4];
        #pragma unroll
        for (int tt = 0; tt < 4; ++tt) {
            f32x4 a = __builtin_amdgcn_mfma_f32_16x16x32_bf16(ah0, bfrag[tt][0], cIn[tt], 0, 0, 0);
            acc[tt]  = __builtin_amdgcn_mfma_f32_16x16x32_bf16(ah1, bfrag[tt][1], a, 0, 0, 0);
        }

        // gate math; C/D layout: row m = quad*4 + r, col = l15
        #pragma unroll
        for (int r = 0; r < 4; ++r) {
            float ig = sigm(acc[0][r]);
            float fg = sigm(acc[1][r]);
            float gg = tanh_fast(acc[2][r]);
            float og = sigm(acc[3][r]);
            c[r] = fg * c[r] + ig * gg;
            float hh = og * tanh_fast(c[r]);
            __builtin_nontemporal_store(hh, optr[r]);   // don't evict pre from L2
            optr[r] += tstep;
            s_h[wb][quad * 4 + r][j] = (short)f2bf(hh);
        }

        // orders LDS h-writes before next step's reads; no vmcnt drain
        LGKM_BARRIER();
    };

    for (int ts = 0; ts < LL; ts += 2) {
        do_step(ts,     PA);
        do_step(ts + 1, PB);
    }
}

extern "C" void kernel_launch(void* const* d_in, const int* in_sizes, int n_in,
                              void* d_out, int out_size, void* d_ws, size_t ws_size,
                              hipStream_t stream) {
    const int*   ids   = (const int*)d_in[0];
    const float* embed = (const float*)d_in[1];
    const float* Wk_f  = (const float*)d_in[2];
    const float* Wr_f  = (const float*)d_in[3];
    const float* b_f   = (const float*)d_in[4];
    const float* Wk_b  = (const float*)d_in[5];
    const float* Wr_b  = (const float*)d_in[6];
    const float* b_b   = (const float*)d_in[7];
    float* out = (float*)d_out;
    float* pre = (float*)d_ws;   // 2 * 6000 * 256 * 4 B = 12.3 MB

    embed_pre_kernel<<<dim3(2 * VBLK), dim3(256), 0, stream>>>(
        embed, Wk_f, b_f, Wk_b, b_b, pre);

    bilstm_mfma<<<dim3(256), dim3(256), 0, stream>>>(ids, Wr_f, Wr_b, pre, out);
}

// Round 5
// 405.514 us; speedup vs baseline: 1.1676x; 1.1676x over previous
//
#include <hip/hip_runtime.h>

#define LL 256   // sequence length
#define EE 64    // embed dim
#define HH 64    // hidden dim
#define GG 256   // 4*H gates
#define VV 6000  // vocab
#define NSEQ 16  // sequences per block (full MFMA tile, no waste)
#define ROWP 72  // padded LDS row stride in bf16 elems (144 B, 16B-aligned)
#define VBLK 375 // phase-1 blocks per direction (6000/16)

typedef __bf16 bf16_t;
typedef bf16_t bf16x8 __attribute__((ext_vector_type(8)));
typedef float  f32x4  __attribute__((ext_vector_type(4)));

union BfPack {
    unsigned short u[8];
    bf16x8 v;
};

__device__ __forceinline__ unsigned short f2bf(float f) {
    return __builtin_bit_cast(unsigned short, (__bf16)f);
}

#define LOG2E 1.44269504088896340736f

// exp2+rcp activations (R1: removed IEEE div sequences). Inf-safe both ends.
__device__ __forceinline__ float sigm(float x) {
    float e = __builtin_amdgcn_exp2f(-LOG2E * x);          // e^{-x}
    return __builtin_amdgcn_rcpf(1.0f + e);
}
__device__ __forceinline__ float tanh_fast(float x) {
    float e = __builtin_amdgcn_exp2f((2.0f * LOG2E) * x);  // e^{2x}
    return 1.0f - 2.0f * __builtin_amdgcn_rcpf(e + 1.0f);
}

// lgkm-only barrier (R0->R1: 567->415 us): cross-wave deps are LDS-only;
// out-stores and pre-gathers stay in flight across it (vmcnt untouched).
// R4 lesson: vmcnt retires IN ISSUE ORDER -- never put slow-ack stores
// (nontemporal/HBM) ahead of gather loads you intend to wait on.
#define LGKM_BARRIER() asm volatile("s_waitcnt lgkmcnt(0)\n\ts_barrier" ::: "memory")

// ---------------- phase 1: embedPre[dir][v][swz(g)] = bf16(embed@Wk + b) ----
// x_t @ Wk == (embed @ Wk)[id] : the whole input projection is a table.
// bf16 table: halves gather traffic (R3 counters: FETCH 375 MB, the gathers
// are the dominant HBM stream). Rounding adds ~4e-5 abs on |pre|~0.02 values.
// Swizzled layout: pos = ((g>>4)&3)*64 + (g&15)*4 + (g>>6), so phase-2 lane
// (w,quad,l15) reads its 4 gate values for one seq-row as ONE dwordx2 at
// elem [id*256 + w*64 + l15*4]; 16 lanes = 128 B contiguous per quad-group.
__global__ __launch_bounds__(256)
void embed_pre_kernel(const float* __restrict__ embed,
                      const float* __restrict__ Wk_f, const float* __restrict__ b_f,
                      const float* __restrict__ Wk_b, const float* __restrict__ b_b,
                      unsigned short* __restrict__ pre)
{
    const int bid = blockIdx.x;
    const int dir = bid / VBLK;
    const int v0  = (bid % VBLK) * 16;
    const float* Wk = dir ? Wk_b : Wk_f;
    const float* bv = dir ? b_b  : b_f;
    unsigned short* dst = pre + (size_t)dir * VV * GG;

    const int tid = threadIdx.x;
    const int r   = tid >> 4;    // v-row 0..15
    const int cg  = tid & 15;    // col residue; thread owns g = k*16+cg

    __shared__ float sW[16][GG];   // 16 KB per E-chunk
    __shared__ float sE[16][17];   // 16 rows x 16 e, padded

    float acc[16];
    #pragma unroll
    for (int k = 0; k < 16; ++k) acc[k] = 0.f;

    for (int ec = 0; ec < 4; ++ec) {
        {   // stage Wk rows ec*16..+15 (coalesced float4) + embed chunk
            int er = tid >> 4;
            int c0 = (tid & 15) * 16;
            const float* src = &Wk[(size_t)(ec * 16 + er) * GG + c0];
            *(float4*)&sW[er][c0 + 0]  = *(const float4*)(src + 0);
            *(float4*)&sW[er][c0 + 4]  = *(const float4*)(src + 4);
            *(float4*)&sW[er][c0 + 8]  = *(const float4*)(src + 8);
            *(float4*)&sW[er][c0 + 12] = *(const float4*)(src + 12);
            sE[er][tid & 15] = embed[(size_t)(v0 + er) * EE + ec * 16 + (tid & 15)];
        }
        __syncthreads();
        #pragma unroll
        for (int e = 0; e < 16; ++e) {
            float xe = sE[r][e];
            #pragma unroll
            for (int k = 0; k < 16; ++k)
                acc[k] += xe * sW[e][k * 16 + cg];   // 16 consecutive banks, CF
        }
        __syncthreads();
    }
    // pos(g)= ((g>>4)&3)*64 + (g&15)*4 + (g>>6); thread writes 4x ushort4:
    // for a=k&3 fixed, b=k>>2=0..3 are 4 consecutive bf16 elems.
    #pragma unroll
    for (int a = 0; a < 4; ++a) {
        ushort4 pk;
        pk.x = f2bf(acc[a]      + bv[(a)      * 16 + cg]);
        pk.y = f2bf(acc[a + 4]  + bv[(a + 4)  * 16 + cg]);
        pk.z = f2bf(acc[a + 8]  + bv[(a + 8)  * 16 + cg]);
        pk.w = f2bf(acc[a + 12] + bv[(a + 12) * 16 + cg]);
        *(ushort4*)&dst[(size_t)(v0 + r) * GG + a * 64 + cg * 4] = pk;
    }
}

// ---------------- phase 2: recurrence only (h@Wr per step) ------------------
// One block = 16 seqs, one direction, 4 waves. Depth-2 ping-pong register
// prefetch (PA even steps, PB odd): no register copy, so the vmcnt wait for a
// buffer happens at its CONSUMING step -> true load->use distance = 2 steps
// (~3500 cyc >> ~900 cyc HBM-miss). Refill is branchless (clamped index) so
// the compiler's static vmcnt counting stays tight. Plain out-stores (L2 ack).
__global__ __launch_bounds__(256, 1)
void bilstm_mfma(const int* __restrict__ ids,
                 const float* __restrict__ Wr_f, const float* __restrict__ Wr_b,
                 const unsigned short* __restrict__ pre,
                 float* __restrict__ out)
{
    const int dir = blockIdx.x >> 7;    // 0 fwd, 1 bwd
    const int grp = blockIdx.x & 127;
    const int n0  = grp * NSEQ;
    const int tid  = threadIdx.x;
    const int w    = tid >> 6;
    const int lane = tid & 63;
    const int l15  = lane & 15;
    const int quad = lane >> 4;
    const int j    = w * 16 + l15;      // gate sub-index in [0,64)

    const float* Wr = dir ? Wr_b : Wr_f;
    const unsigned short* preT = pre + (size_t)dir * VV * GG;
    const int coff = w * 64 + l15 * 4;  // lane's fixed swizzled elem offset

    __shared__ __align__(16) short s_h[2][NSEQ][ROWP];  // 4.5 KB
    __shared__ int s_ids[NSEQ][LL + 1];                 // padded: row stride 257

    // stage ids (coalesced)
    for (int p = tid; p < NSEQ * LL; p += 256) {
        int m = p >> 8, t = p & 255;
        s_ids[m][t] = ids[(size_t)(n0 + m) * LL + t];
    }
    // zero both h buffers (h0 = 0)
    for (int p = tid; p < 2 * NSEQ * ROWP; p += 256)
        (&s_h[0][0][0])[p] = 0;

    __syncthreads();

    // Wr B-fragments only (K=64): lane holds B[k = kc*32 + quad*8 + e][l15]
    bf16x8 bfrag[4][2];
    #pragma unroll
    for (int tt = 0; tt < 4; ++tt) {
        int g = tt * 64 + j;
        #pragma unroll
        for (int kc = 0; kc < 2; ++kc) {
            BfPack pk;
            #pragma unroll
            for (int e = 0; e < 8; ++e) {
                int kg = kc * 32 + quad * 8 + e;
                pk.u[e] = f2bf(Wr[(size_t)kg * GG + g]);
            }
            bfrag[tt][kc] = pk.v;
        }
    }

    // ping-pong prefetch buffers (bf16 pairs): PA serves even ts, PB odd ts
    uint2 PA[4], PB[4];
    {
        int t0 = dir ? (LL - 1) : 0;
        int t1 = dir ? (LL - 2) : 1;
        #pragma unroll
        for (int r = 0; r < 4; ++r) {
            PA[r] = *(const uint2*)&preT[(size_t)s_ids[quad * 4 + r][t0] * GG + coff];
            PB[r] = *(const uint2*)&preT[(size_t)s_ids[quad * 4 + r][t1] * GG + coff];
        }
    }

    float c[4] = {0.f, 0.f, 0.f, 0.f};

    // strength-reduced out pointers: advance +-256 floats per timestep
    const int tstep = dir ? -(2 * HH) : (2 * HH);
    float* optr[4];
    {
        const int t0 = dir ? (LL - 1) : 0;
        #pragma unroll
        for (int r = 0; r < 4; ++r)
            optr[r] = out + ((size_t)(n0 + quad * 4 + r) * LL + t0) * (2 * HH) + dir * HH + j;
    }

    // one sub-step; P is the ping-pong buffer owning this parity
    auto do_step = [&](int ts, uint2 (&P)[4]) {
        const int rb = ts & 1, wb = (ts + 1) & 1;

        // h A-fragments first (lgkm latency overlaps the vmcnt wait below)
        bf16x8 ah0 = *(const bf16x8*)&s_h[rb][l15][quad * 8];
        bf16x8 ah1 = *(const bf16x8*)&s_h[rb][l15][32 + quad * 8];

        // consume P into f32 C-seeds: bf16->f32 is <<16 / &0xffff0000, and the
        // 4x4 transpose falls out of the unpack for free.
        f32x4 cIn[4];
        #pragma unroll
        for (int r = 0; r < 4; ++r) {
            cIn[0][r] = __uint_as_float(P[r].x << 16);
            cIn[1][r] = __uint_as_float(P[r].x & 0xffff0000u);
            cIn[2][r] = __uint_as_float(P[r].y << 16);
            cIn[3][r] = __uint_as_float(P[r].y & 0xffff0000u);
        }

        // branchless refill of P for ts+2 (clamped: tail loads re-read a valid
        // row and are simply unused)
        {
            int tn = dir ? (LL - 3 - ts) : (ts + 2);
            tn = tn < 0 ? 0 : (tn > LL - 1 ? LL - 1 : tn);
            #pragma unroll
            for (int r = 0; r < 4; ++r)
                P[r] = *(const uint2*)&preT[(size_t)s_ids[quad * 4 + r][tn] * GG + coff];
        }

        // z = pre (C-seed: bias + x@Wk folded) + h@Wr, 4 independent chains
        f32x4 acc[4];
        #pragma unroll
        for (int tt = 0; tt < 4; ++tt) {
            f32x4 a = __builtin_amdgcn_mfma_f32_16x16x32_bf16(ah0, bfrag[tt][0], cIn[tt], 0, 0, 0);
            acc[tt]  = __builtin_amdgcn_mfma_f32_16x16x32_bf16(ah1, bfrag[tt][1], a, 0, 0, 0);
        }

        // gate math; C/D layout: row m = quad*4 + r, col = l15
        #pragma unroll
        for (int r = 0; r < 4; ++r) {
            float ig = sigm(acc[0][r]);
            float fg = sigm(acc[1][r]);
            float gg = tanh_fast(acc[2][r]);
            float og = sigm(acc[3][r]);
            c[r] = fg * c[r] + ig * gg;
            float hh = og * tanh_fast(c[r]);
            *optr[r] = hh;                       // plain store: fast L2 ack
            optr[r] += tstep;
            s_h[wb][quad * 4 + r][j] = (short)f2bf(hh);
        }

        // orders LDS h-writes before next step's reads; no vmcnt drain
        LGKM_BARRIER();
    };

    for (int ts = 0; ts < LL; ts += 2) {
        do_step(ts,     PA);
        do_step(ts + 1, PB);
    }
}

extern "C" void kernel_launch(void* const* d_in, const int* in_sizes, int n_in,
                              void* d_out, int out_size, void* d_ws, size_t ws_size,
                              hipStream_t stream) {
    const int*   ids   = (const int*)d_in[0];
    const float* embed = (const float*)d_in[1];
    const float* Wk_f  = (const float*)d_in[2];
    const float* Wr_f  = (const float*)d_in[3];
    const float* b_f   = (const float*)d_in[4];
    const float* Wk_b  = (const float*)d_in[5];
    const float* Wr_b  = (const float*)d_in[6];
    const float* b_b   = (const float*)d_in[7];
    float* out = (float*)d_out;
    unsigned short* pre = (unsigned short*)d_ws;   // 2*6000*256*2 B = 6.1 MB

    embed_pre_kernel<<<dim3(2 * VBLK), dim3(256), 0, stream>>>(
        embed, Wk_f, b_f, Wk_b, b_b, pre);

    bilstm_mfma<<<dim3(256), dim3(256), 0, stream>>>(ids, Wr_f, Wr_b, pre, out);
}